// Round 1
// baseline (26.902 us; speedup 1.0000x reference)
//
#include <hip/hip_runtime.h>

#define BATCH 4096
#define NCTRL 64
#define SDIM  2048
#define SBLK  256

__global__ __launch_bounds__(SBLK) void curve_eval_kernel(
    const float4* __restrict__ cp,     // [B, NCTRL] as float4 (x,y,z,w)
    const int*    __restrict__ span,   // [SDIM]
    const float4* __restrict__ basis,  // [SDIM] as float4
    float4*       __restrict__ out)    // [B*SDIM*3/4] float4
{
    __shared__ float4 cp_s[NCTRL];
    __shared__ float  out_s[SBLK * 3];

    const int b   = blockIdx.y;
    const int s0  = blockIdx.x * SBLK;
    const int tid = threadIdx.x;

    // Stage this curve's control points into LDS (1 KB).
    if (tid < NCTRL) {
        cp_s[tid] = cp[(size_t)b * NCTRL + tid];
    }
    __syncthreads();

    const int s = s0 + tid;
    const int sp = span[s];              // in [3, 63]
    const float4 bas = basis[s];

    const float4 r0 = cp_s[sp - 3];
    const float4 r1 = cp_s[sp - 2];
    const float4 r2 = cp_s[sp - 1];
    const float4 r3 = cp_s[sp - 0];

    float4 acc;
    acc.x = bas.x * r0.x + bas.y * r1.x + bas.z * r2.x + bas.w * r3.x;
    acc.y = bas.x * r0.y + bas.y * r1.y + bas.z * r2.y + bas.w * r3.y;
    acc.z = bas.x * r0.z + bas.y * r1.z + bas.z * r2.z + bas.w * r3.z;
    acc.w = bas.x * r0.w + bas.y * r1.w + bas.z * r2.w + bas.w * r3.w;

    const float invw = 1.0f / acc.w;     // full-precision divide sequence
    out_s[tid * 3 + 0] = acc.x * invw;   // stride-3 LDS writes: 2-way max, free
    out_s[tid * 3 + 1] = acc.y * invw;
    out_s[tid * 3 + 2] = acc.z * invw;
    __syncthreads();

    // Coalesced flush: 256*3 floats = 192 float4 per block, fully contiguous.
    // Base in float4 units: (b*SDIM + s0)*3/4 — s0 multiple of 256 => divisible by 4.
    const size_t base4 = ((size_t)b * SDIM + (size_t)s0) * 3u / 4u;
    if (tid < (SBLK * 3 / 4)) {
        const float4 v = reinterpret_cast<const float4*>(out_s)[tid];
        out[base4 + tid] = v;
    }
}

extern "C" void kernel_launch(void* const* d_in, const int* in_sizes, int n_in,
                              void* d_out, int out_size, void* d_ws, size_t ws_size,
                              hipStream_t stream) {
    const float4* cp    = (const float4*)d_in[0];  // [4096,64,4] f32
    const int*    span  = (const int*)d_in[1];     // [2048] i32
    const float4* basis = (const float4*)d_in[2];  // [2048,4] f32
    float4*       out   = (float4*)d_out;          // [4096,2048,3] f32

    dim3 grid(SDIM / SBLK, BATCH);
    curve_eval_kernel<<<grid, SBLK, 0, stream>>>(cp, span, basis, out);
}